// Round 22
// baseline (132.802 us; speedup 1.0000x reference)
//
#include <hip/hip_runtime.h>
#include <hip/hip_bf16.h>
#include <cstdint>
#include <cstddef>

#define DMODEL 1024
#define NHEADS 16
#define DK 64
#define SEQ 2048
#define BATCH 2
#define NT2 (SEQ / 64)

typedef short bf16x8 __attribute__((ext_vector_type(8)));
typedef float f32x4 __attribute__((ext_vector_type(4)));
typedef float f32x16 __attribute__((ext_vector_type(16)));
typedef unsigned int u32x2 __attribute__((ext_vector_type(2)));
typedef unsigned int u32x4 __attribute__((ext_vector_type(4)));

typedef const __attribute__((address_space(1))) void* gas_ptr;
typedef __attribute__((address_space(3))) void* las_ptr;

__device__ __forceinline__ void gld_lds16(const void* g, void* l) {
    __builtin_amdgcn_global_load_lds((gas_ptr)g, (las_ptr)l, 16, 0, 0);
}

__device__ __forceinline__ ushort f2bf_u(float f) {
    uint32_t x = __float_as_uint(f);
    x += 0x7fff + ((x >> 16) & 1);   // RNE
    return (ushort)(x >> 16);
}

// ------- fused cast fp32 -> bf16 (7 arrays) + mask->bias, 1 launch ----------
__global__ __launch_bounds__(256) void cast_all(
        const float* __restrict__ q, const float* __restrict__ k,
        const float* __restrict__ v, const float* __restrict__ Wq,
        const float* __restrict__ Wk, const float* __restrict__ Wv,
        const float* __restrict__ Wo, const int* __restrict__ mask,
        ushort* __restrict__ qb, ushort* __restrict__ kb, ushort* __restrict__ vb,
        ushort* __restrict__ Wqb, ushort* __restrict__ Wkb,
        ushort* __restrict__ Wvb, ushort* __restrict__ Wob,
        float* __restrict__ mb) {
    int bid = blockIdx.x;
    if (bid >= 16384) {                       // mask -> additive bias (4 blocks)
        int i = (bid - 16384) * 1024 + threadIdx.x * 4;
        int4 mk = *reinterpret_cast<const int4*>(mask + i);
        float4 o;
        o.x = mk.x ? 0.f : -1e9f;
        o.y = mk.y ? 0.f : -1e9f;
        o.z = mk.z ? 0.f : -1e9f;
        o.w = mk.w ? 0.f : -1e9f;
        *reinterpret_cast<float4*>(mb + i) = o;
        return;
    }
    const float* src; ushort* dst; int base;
    if      (bid <  4096) { src = q;  dst = qb;  base = bid; }
    else if (bid <  8192) { src = k;  dst = kb;  base = bid - 4096; }
    else if (bid < 12288) { src = v;  dst = vb;  base = bid - 8192; }
    else if (bid < 13312) { src = Wq; dst = Wqb; base = bid - 12288; }
    else if (bid < 14336) { src = Wk; dst = Wkb; base = bid - 13312; }
    else if (bid < 15360) { src = Wv; dst = Wvb; base = bid - 14336; }
    else                  { src = Wo; dst = Wob; base = bid - 15360; }
    int i = base * 1024 + threadIdx.x * 4;
    float4 f = *reinterpret_cast<const float4*>(src + i);
    ushort4 o;
    o.x = f2bf_u(f.x); o.y = f2bf_u(f.y); o.z = f2bf_u(f.z); o.w = f2bf_u(f.w);
    *reinterpret_cast<ushort4*>(dst + i) = o;
}

// ---------------- fused QKV projection GEMM (128x128, BK=64) ----------------
__global__ __launch_bounds__(256) void gemm_qkv(
        const ushort* __restrict__ A,     // 12288 x 1024
        const ushort* __restrict__ Wall,  // 3072 x 1024 (Wq|Wk|Wv)
        const float* __restrict__ bq, const float* __restrict__ bk,
        const float* __restrict__ bv,
        ushort* __restrict__ Qh, ushort* __restrict__ Kh, ushort* __restrict__ Vt) {
    __shared__ ushort As[128 * 64];   // 16KB
    __shared__ ushort Bs[128 * 64];   // 16KB
    const int tid = threadIdx.x;
    const int w = tid >> 6, lane = tid & 63;
    const int lr = lane & 15, lg = lane >> 4;
    int lid = (blockIdx.x & 7) * 96 + (blockIdx.x >> 3);
    const int tMg = (lid >> 3) << 7;
    const int tN  = (lid & 7) << 7;
    const int g   = tMg >> 12;                // 0=Q 1=K 2=V
    const ushort* W = Wall + (size_t)g * 1024 * 1024;
    const float* bias = (g == 0) ? bq : (g == 1 ? bk : bv);
    const int wr = (w >> 1) * 64, wc = (w & 1) * 64;

    f32x4 acc[4][4] = {};

    const ushort* gAsrc[4];
    const ushort* gBsrc[4];
#pragma unroll
    for (int i = 0; i < 4; i++) {
        int slot = (w * 4 + i) * 64 + lane;
        int row = slot >> 3, sr = slot & 7;
        int cd = sr ^ (row & 7);
        gAsrc[i] = A + (size_t)(tMg + row) * 1024 + cd * 8;
        gBsrc[i] = W + (size_t)(tN + row) * 1024 + cd * 8;
    }

    for (int k0 = 0; k0 < 1024; k0 += 64) {
#pragma unroll
        for (int i = 0; i < 4; i++)
            gld_lds16(gAsrc[i] + k0, As + (w * 4 + i) * 512);
#pragma unroll
        for (int i = 0; i < 4; i++)
            gld_lds16(gBsrc[i] + k0, Bs + (w * 4 + i) * 512);
        __syncthreads();

#pragma unroll
        for (int ks = 0; ks < 2; ks++) {
            bf16x8 af[4], bfr[4];
#pragma unroll
            for (int i = 0; i < 4; i++)
                af[i] = *(const bf16x8*)(As + (wr + i * 16 + lr) * 64 +
                                         (((ks * 4 + lg) ^ (lr & 7)) * 8));
#pragma unroll
            for (int i = 0; i < 4; i++)
                bfr[i] = *(const bf16x8*)(Bs + (wc + i * 16 + lr) * 64 +
                                          (((ks * 4 + lg) ^ (lr & 7)) * 8));
#pragma unroll
            for (int mi = 0; mi < 4; mi++)
#pragma unroll
                for (int ni = 0; ni < 4; ni++)
                    acc[mi][ni] = __builtin_amdgcn_mfma_f32_16x16x32_bf16(
                        af[mi], bfr[ni], acc[mi][ni], 0, 0, 0);
        }
        __syncthreads();
    }

#pragma unroll
    for (int mi = 0; mi < 4; mi++) {
        const int row0 = tMg + wr + mi * 16 + lg * 4;
#pragma unroll
        for (int ni = 0; ni < 4; ni++) {
            const int col = tN + wc + ni * 16 + lr;
            const int h = col >> 6, d = col & (DK - 1);
            const float bvv = bias[col];
            if (g == 2) {
                int mloc = row0 & 4095;
                int b = mloc >> 11, s0 = mloc & (SEQ - 1);
                ushort4 o4;
                o4.x = f2bf_u(acc[mi][ni][0] + bvv);
                o4.y = f2bf_u(acc[mi][ni][1] + bvv);
                o4.z = f2bf_u(acc[mi][ni][2] + bvv);
                o4.w = f2bf_u(acc[mi][ni][3] + bvv);
                *reinterpret_cast<ushort4*>(
                    &Vt[(((size_t)(b * NHEADS + h) * DK + d) * SEQ) + s0]) = o4;
            } else {
#pragma unroll
                for (int r = 0; r < 4; r++) {
                    float vv = acc[mi][ni][r] + bvv;
                    int mloc = (row0 + r) & 4095;
                    int b = mloc >> 11, s = mloc & (SEQ - 1);
                    if (g == 0)
                        Qh[(((size_t)(b * NHEADS + h) * SEQ + s) * DK) + d] = f2bf_u(vv);
                    else
                        Kh[(((size_t)(b * NHEADS + h) * SEQ + s) * DK) + d] = f2bf_u(vv);
                }
            }
        }
    }
}

// ---------------- output GEMM (64x128 tile, BK=64, XOR-swizzled LDS) ---------
__global__ __launch_bounds__(256) void gemm_out(
        const ushort* __restrict__ A,   // M x K bf16 row-major (ctx)
        const ushort* __restrict__ W,   // N x K bf16 row-major (Wo)
        const float* __restrict__ bias, // N
        float* __restrict__ out, int M, int N, int K) {
    __shared__ ushort As[64 * 64];     // 8KB
    __shared__ ushort Bs[128 * 64];    // 16KB
    const int tid = threadIdx.x;
    const int w = tid >> 6, lane = tid & 63;
    const int lr = lane & 15, lg = lane >> 4;
    const int nTiles = N >> 7;
    const int cpx = gridDim.x >> 3;
    int lid = (blockIdx.x & 7) * cpx + (blockIdx.x >> 3);
    const int tM = (lid / nTiles) << 6;
    const int tN = (lid % nTiles) << 7;
    const int wr = (w >> 1) * 32, wc = (w & 1) * 64;

    f32x4 acc[2][4] = {};

    const ushort* gAsrc[2];
    const ushort* gBsrc[4];
#pragma unroll
    for (int i = 0; i < 2; i++) {
        int slot = (w * 2 + i) * 64 + lane;
        int row = slot >> 3, sr = slot & 7;
        int cd = sr ^ (row & 7);
        gAsrc[i] = A + (size_t)(tM + row) * K + cd * 8;
    }
#pragma unroll
    for (int i = 0; i < 4; i++) {
        int slot = (w * 4 + i) * 64 + lane;
        int row = slot >> 3, sr = slot & 7;
        int cd = sr ^ (row & 7);
        gBsrc[i] = W + (size_t)(tN + row) * K + cd * 8;
    }

    for (int k0 = 0; k0 < K; k0 += 64) {
#pragma unroll
        for (int i = 0; i < 2; i++)
            gld_lds16(gAsrc[i] + k0, As + (w * 2 + i) * 512);
#pragma unroll
        for (int i = 0; i < 4; i++)
            gld_lds16(gBsrc[i] + k0, Bs + (w * 4 + i) * 512);
        __syncthreads();

#pragma unroll
        for (int ks = 0; ks < 2; ks++) {
            bf16x8 af[2], bfr[4];
#pragma unroll
            for (int i = 0; i < 2; i++)
                af[i] = *(const bf16x8*)(As + (wr + i * 16 + lr) * 64 +
                                         (((ks * 4 + lg) ^ (lr & 7)) * 8));
#pragma unroll
            for (int i = 0; i < 4; i++)
                bfr[i] = *(const bf16x8*)(Bs + (wc + i * 16 + lr) * 64 +
                                          (((ks * 4 + lg) ^ (lr & 7)) * 8));
#pragma unroll
            for (int mi = 0; mi < 2; mi++)
#pragma unroll
                for (int ni = 0; ni < 4; ni++)
                    acc[mi][ni] = __builtin_amdgcn_mfma_f32_16x16x32_bf16(
                        af[mi], bfr[ni], acc[mi][ni], 0, 0, 0);
        }
        __syncthreads();
    }

#pragma unroll
    for (int mi = 0; mi < 2; mi++) {
        const int row0 = tM + wr + mi * 16 + lg * 4;
#pragma unroll
        for (int ni = 0; ni < 4; ni++) {
            const int col = tN + wc + ni * 16 + lr;
            const float bv = bias[col];
#pragma unroll
            for (int r = 0; r < 4; r++)
                out[(size_t)(row0 + r) * N + col] = acc[mi][ni][r] + bv;
        }
    }
}

// ------- attention: KVBLK=64, distance-2 prefetch, counted vmcnt barrier -----
// 3-deep shared LDS buffers; STAGE(t+2) issued at iter-t top. Barrier is raw
// s_barrier preceded by s_waitcnt vmcnt(4): the newest stage's 4 loads stay in
// flight ACROSS the barrier (T4), giving each load ~1 extra iteration to cover
// HBM-miss latency. WAR safe: stage(t+2) overwrites buf((t-1)%3), whose reads
// completed (consumed by MFMA) before the previous barrier.
#define SCALE2 0.18033688011120542f   // 0.125 * log2(e)

__device__ __forceinline__ bf16x8 pack_pa(const float* p) {
    uint a, b, c, d;
    asm("v_cvt_pk_bf16_f32 %0, %1, %2" : "=v"(a) : "v"(p[0]), "v"(p[1]));
    asm("v_cvt_pk_bf16_f32 %0, %1, %2" : "=v"(b) : "v"(p[4]), "v"(p[5]));
    asm("v_cvt_pk_bf16_f32 %0, %1, %2" : "=v"(c) : "v"(p[2]), "v"(p[3]));
    asm("v_cvt_pk_bf16_f32 %0, %1, %2" : "=v"(d) : "v"(p[6]), "v"(p[7]));
    asm("v_permlane32_swap_b32 %0, %1" : "+v"(a), "+v"(b));
    asm("v_permlane32_swap_b32 %0, %1" : "+v"(c), "+v"(d));
    union { u32x4 u; bf16x8 h; } cv;
    cv.u = (u32x4){a, c, b, d};
    return cv.h;
}

__global__ __launch_bounds__(256) void attn_fwd32(
        const ushort* __restrict__ Qh, const ushort* __restrict__ Kh,
        const ushort* __restrict__ Vt, const float* __restrict__ mbias,
        ushort* __restrict__ ctx) {
    __shared__ ushort Ks[3][2][2048];   // 24KB (3-deep)
    __shared__ ushort Vs[3][2][2048];   // 24KB
    __shared__ float  Ml[SEQ];          // 8KB  -> 56KB total, 2 blocks/CU

    const int tid = threadIdx.x;
    const int w = tid >> 6;
    const int l = tid & 63;
    const int q32 = l & 31, hi = l >> 5;
    const int q7 = l & 7;

    int lid = (blockIdx.x & 7) * 64 + (blockIdx.x >> 3);
    const int qblk = lid & 15;
    const int bh = lid >> 4;
    const int b = bh >> 4;
    const int h = bh & 15;
    const int q0 = qblk * 128 + w * 32;

    const ushort* Qp = Qh + (size_t)bh * SEQ * DK + (size_t)(q0 + q32) * DK + hi * 8;
    const ushort* Kg = Kh + (size_t)bh * SEQ * DK;
    const ushort* Vg = Vt + (size_t)bh * DK * SEQ;

    const int srow = tid >> 3;
    const int scs  = (tid & 7) ^ (srow & 7);
    const ushort* Ksrc = Kg + (size_t)srow * DK + scs * 8;
    const ushort* Vsrc = Vg + (size_t)(srow + ((scs & 4) << 3)) * SEQ + (scs & 3) * 8;

    {
        const float* mg = mbias + (size_t)b * SEQ;
        gld_lds16(mg + tid * 4,        &Ml[w * 256]);
        gld_lds16(mg + 1024 + tid * 4, &Ml[1024 + w * 256]);
    }

    auto STAGE = [&](int buf, int t) {
        const int kv0 = t * 64;
        gld_lds16(Ksrc + (size_t)kv0 * DK,        &Ks[buf][0][w * 512]);
        gld_lds16(Ksrc + (size_t)(kv0 + 32) * DK, &Ks[buf][1][w * 512]);
        gld_lds16(Vsrc + kv0,                     &Vs[buf][0][w * 512]);
        gld_lds16(Vsrc + kv0 + 32,                &Vs[buf][1][w * 512]);
    };

    bf16x8 qf[4];
#pragma unroll
    for (int dc = 0; dc < 4; dc++)
        qf[dc] = *(const bf16x8*)(Qp + dc * 16);

    const short one_s = (short)0x3F80;
    const bf16x8 ones = {one_s, one_s, one_s, one_s, one_s, one_s, one_s, one_s};

    f32x16 c0 = {}, c1 = {};
    f32x16 lacc = {};

    STAGE(0, 0);
    STAGE(1, 1);
    __syncthreads();       // one-time full drain: Ml + tiles 0,1 resident

    int buf = 0, bufn2 = 2;
    for (int t = 0; t < NT2; ++t) {
        if (t + 2 < NT2) STAGE(bufn2, t + 2);

        const int kv0 = t * 64;

        bf16x8 kf0[4], kf1[4];
#pragma unroll
        for (int dc = 0; dc < 4; dc++)
            kf0[dc] = *(const bf16x8*)(&Ks[buf][0][q32 * 64 + (((dc * 2 + hi) ^ q7) * 8)]);
        f32x16 s0 = {}, s1 = {};
        __builtin_amdgcn_s_setprio(1);
#pragma unroll
        for (int dc = 0; dc < 4; dc++)
            s0 = __builtin_amdgcn_mfma_f32_32x32x16_bf16(kf0[dc], qf[dc], s0, 0, 0, 0);
        __builtin_amdgcn_s_setprio(0);
#pragma unroll
        for (int dc = 0; dc < 4; dc++)
            kf1[dc] = *(const bf16x8*)(&Ks[buf][1][q32 * 64 + (((dc * 2 + hi) ^ q7) * 8)]);
        __builtin_amdgcn_s_setprio(1);
#pragma unroll
        for (int dc = 0; dc < 4; dc++)
            s1 = __builtin_amdgcn_mfma_f32_32x32x16_bf16(kf1[dc], qf[dc], s1, 0, 0, 0);
        __builtin_amdgcn_s_setprio(0);

        float e0[16];
#pragma unroll
        for (int g = 0; g < 4; g++) {
            float4 mb0 = *reinterpret_cast<const float4*>(&Ml[kv0 + g * 8 + hi * 4]);
#pragma unroll
            for (int j = 0; j < 4; j++)
                e0[g * 4 + j] = __builtin_amdgcn_exp2f(
                    fmaf(s0[g * 4 + j], SCALE2, reinterpret_cast<const float*>(&mb0)[j]));
        }
        bf16x8 pa00 = pack_pa(e0);
        bf16x8 pa01 = pack_pa(e0 + 8);
        bf16x8 vc0[4];
#pragma unroll
        for (int dt = 0; dt < 2; dt++)
#pragma unroll
            for (int ks = 0; ks < 2; ks++)
                vc0[dt * 2 + ks] = *(const bf16x8*)(&Vs[buf][0][q32 * 64 + (((dt * 4 + ks * 2 + hi) ^ q7) * 8)]);
        __builtin_amdgcn_s_setprio(1);
        c0 = __builtin_amdgcn_mfma_f32_32x32x16_bf16(pa00, vc0[0], c0, 0, 0, 0);
        c1 = __builtin_amdgcn_mfma_f32_32x32x16_bf16(pa00, vc0[2], c1, 0, 0, 0);
        c0 = __builtin_amdgcn_mfma_f32_32x32x16_bf16(pa01, vc0[1], c0, 0, 0, 0);
        c1 = __builtin_amdgcn_mfma_f32_32x32x16_bf16(pa01, vc0[3], c1, 0, 0, 0);
        lacc = __builtin_amdgcn_mfma_f32_32x32x16_bf16(pa00, ones, lacc, 0, 0, 0);
        lacc = __builtin_amdgcn_mfma_f32_32x32x16_bf16(pa01, ones, lacc, 0, 0, 0);
        __builtin_amdgcn_s_setprio(0);

        float e1[16];
#pragma unroll
        for (int g = 0; g < 4; g++) {
            float4 mb1 = *reinterpret_cast<const float4*>(&Ml[kv0 + 32 + g * 8 + hi * 4]);
#pragma unroll
            for (int j = 0; j < 4; j++)
                e1[g * 4 + j] = __builtin_amdgcn_exp2f(
                    fmaf(s1[g * 4 + j], SCALE2, reinterpret_cast<const float*>(&mb1)[j]));
        }
        bf16x8 pa10 = pack_pa(e1);
        bf16x8 pa11 = pack_pa(e1 + 8);
        bf16x8 vc1[4];
#pragma unroll
        for (int dt = 0; dt < 2; dt++)
#pragma unroll
            for (int ks = 0; ks < 2; ks++)
                vc1[dt * 2 + ks] = *(const bf16x8*)(&Vs[buf][1][q32 * 64 + (((dt * 4 + ks * 2 + hi) ^ q7) * 8)]);
        __builtin_amdgcn_s_setprio(1);
        c0 = __builtin_amdgcn_mfma_f32_32x32x16_bf16(pa10, vc1[0], c0, 0, 0, 0);
        c1 = __builtin_amdgcn_mfma_f32_32x32x16_bf16(pa10, vc1[2], c1, 0, 0, 0);
        c0 = __builtin_amdgcn_mfma_f32_32x32x16_bf16(pa11, vc1[1], c0, 0, 0, 0);
        c1 = __builtin_amdgcn_mfma_f32_32x32x16_bf16(pa11, vc1[3], c1, 0, 0, 0);
        lacc = __builtin_amdgcn_mfma_f32_32x32x16_bf16(pa10, ones, lacc, 0, 0, 0);
        lacc = __builtin_amdgcn_mfma_f32_32x32x16_bf16(pa11, ones, lacc, 0, 0, 0);
        __builtin_amdgcn_s_setprio(0);

        // counted-vmcnt barrier: keep stage(t+2)'s 4 loads in flight (T4);
        // ensures stage(t+1) resident for next iter. Tail: full drain.
        if (t + 2 < NT2) asm volatile("s_waitcnt vmcnt(4)" ::: "memory");
        else             asm volatile("s_waitcnt vmcnt(0)" ::: "memory");
        __builtin_amdgcn_sched_barrier(0);
        __builtin_amdgcn_s_barrier();

        buf   = (buf == 2) ? 0 : buf + 1;
        bufn2 = (bufn2 == 2) ? 0 : bufn2 + 1;
    }

#pragma unroll
    for (int r = 0; r < 16; r++) {
        int crow = (r & 3) + 8 * (r >> 2) + 4 * hi;
        float rlT = __builtin_amdgcn_rcpf(lacc[r]);
        int qq = q0 + crow;
        size_t base = (size_t)(b * SEQ + qq) * DMODEL + h * DK;
        ctx[base + q32]      = f2bf_u(c0[r] * rlT);
        ctx[base + 32 + q32] = f2bf_u(c1[r] * rlT);
    }
}

extern "C" void kernel_launch(void* const* d_in, const int* in_sizes, int n_in,
                              void* d_out, int out_size, void* d_ws, size_t ws_size,
                              hipStream_t stream) {
    const float* q    = (const float*)d_in[0];
    const float* k    = (const float*)d_in[1];
    const float* v    = (const float*)d_in[2];
    const int*   mask = (const int*)d_in[3];
    const float* Wq   = (const float*)d_in[4];
    const float* bq   = (const float*)d_in[5];
    const float* Wk   = (const float*)d_in[6];
    const float* bk   = (const float*)d_in[7];
    const float* Wv   = (const float*)d_in[8];
    const float* bv   = (const float*)d_in[9];
    const float* Wo   = (const float*)d_in[10];
    const float* bo   = (const float*)d_in[11];

    char* ws = (char*)d_ws;
    ushort* qb   = (ushort*)(ws + (size_t)0);          // [qb|kb|vb] = 12288x1024
    ushort* kb   = (ushort*)(ws + ((size_t)8  << 20));
    ushort* vb   = (ushort*)(ws + ((size_t)16 << 20));
    ushort* Wqb  = (ushort*)(ws + ((size_t)24 << 20)); // [Wqb|Wkb|Wvb]
    ushort* Wkb  = (ushort*)(ws + ((size_t)26 << 20));
    ushort* Wvb  = (ushort*)(ws + ((size_t)28 << 20));
    ushort* Wob  = (ushort*)(ws + ((size_t)30 << 20));
    ushort* Qh   = (ushort*)(ws + ((size_t)32 << 20));
    ushort* Kh   = (ushort*)(ws + ((size_t)40 << 20));
    ushort* Vt   = (ushort*)(ws + ((size_t)48 << 20));
    ushort* ctxb = (ushort*)(ws + ((size_t)56 << 20));
    float*  mbias = (float*)d_out;   // written by cast_all, read by attn,
                                     // then d_out fully overwritten by gemm_out

    cast_all<<<16388, 256, 0, stream>>>(q, k, v, Wq, Wk, Wv, Wo, mask,
                                        qb, kb, vb, Wqb, Wkb, Wvb, Wob, mbias);

    gemm_qkv<<<768, 256, 0, stream>>>(qb, Wqb, bq, bk, bv, Qh, Kh, Vt);

    attn_fwd32<<<BATCH * NHEADS * (SEQ / 128), 256, 0, stream>>>(Qh, Kh, Vt, mbias, ctxb);

    const int M = BATCH * SEQ;
    gemm_out<<<(M / 64) * (DMODEL / 128), 256, 0, stream>>>(
        ctxb, Wob, bo, (float*)d_out, M, DMODEL, DMODEL);
}

// Round 23
// 131.075 us; speedup vs baseline: 1.0132x; 1.0132x over previous
//
#include <hip/hip_runtime.h>
#include <hip/hip_bf16.h>
#include <cstdint>
#include <cstddef>

#define DMODEL 1024
#define NHEADS 16
#define DK 64
#define SEQ 2048
#define BATCH 2
#define NT2 (SEQ / 64)

typedef short bf16x8 __attribute__((ext_vector_type(8)));
typedef float f32x4 __attribute__((ext_vector_type(4)));
typedef float f32x16 __attribute__((ext_vector_type(16)));
typedef unsigned int u32x2 __attribute__((ext_vector_type(2)));
typedef unsigned int u32x4 __attribute__((ext_vector_type(4)));

typedef const __attribute__((address_space(1))) void* gas_ptr;
typedef __attribute__((address_space(3))) void* las_ptr;

__device__ __forceinline__ void gld_lds16(const void* g, void* l) {
    __builtin_amdgcn_global_load_lds((gas_ptr)g, (las_ptr)l, 16, 0, 0);
}

__device__ __forceinline__ ushort f2bf_u(float f) {
    uint32_t x = __float_as_uint(f);
    x += 0x7fff + ((x >> 16) & 1);   // RNE
    return (ushort)(x >> 16);
}

// ------- fused cast fp32 -> bf16 (7 arrays) + mask->bias, 1 launch ----------
__global__ __launch_bounds__(256) void cast_all(
        const float* __restrict__ q, const float* __restrict__ k,
        const float* __restrict__ v, const float* __restrict__ Wq,
        const float* __restrict__ Wk, const float* __restrict__ Wv,
        const float* __restrict__ Wo, const int* __restrict__ mask,
        ushort* __restrict__ qb, ushort* __restrict__ kb, ushort* __restrict__ vb,
        ushort* __restrict__ Wqb, ushort* __restrict__ Wkb,
        ushort* __restrict__ Wvb, ushort* __restrict__ Wob,
        float* __restrict__ mb) {
    int bid = blockIdx.x;
    if (bid >= 16384) {                       // mask -> additive bias (4 blocks)
        int i = (bid - 16384) * 1024 + threadIdx.x * 4;
        int4 mk = *reinterpret_cast<const int4*>(mask + i);
        float4 o;
        o.x = mk.x ? 0.f : -1e9f;
        o.y = mk.y ? 0.f : -1e9f;
        o.z = mk.z ? 0.f : -1e9f;
        o.w = mk.w ? 0.f : -1e9f;
        *reinterpret_cast<float4*>(mb + i) = o;
        return;
    }
    const float* src; ushort* dst; int base;
    if      (bid <  4096) { src = q;  dst = qb;  base = bid; }
    else if (bid <  8192) { src = k;  dst = kb;  base = bid - 4096; }
    else if (bid < 12288) { src = v;  dst = vb;  base = bid - 8192; }
    else if (bid < 13312) { src = Wq; dst = Wqb; base = bid - 12288; }
    else if (bid < 14336) { src = Wk; dst = Wkb; base = bid - 13312; }
    else if (bid < 15360) { src = Wv; dst = Wvb; base = bid - 14336; }
    else                  { src = Wo; dst = Wob; base = bid - 15360; }
    int i = base * 1024 + threadIdx.x * 4;
    float4 f = *reinterpret_cast<const float4*>(src + i);
    ushort4 o;
    o.x = f2bf_u(f.x); o.y = f2bf_u(f.y); o.z = f2bf_u(f.z); o.w = f2bf_u(f.w);
    *reinterpret_cast<ushort4*>(dst + i) = o;
}

// ---------------- fused QKV projection GEMM (128x128, BK=64) ----------------
__global__ __launch_bounds__(256) void gemm_qkv(
        const ushort* __restrict__ A,     // 12288 x 1024
        const ushort* __restrict__ Wall,  // 3072 x 1024 (Wq|Wk|Wv)
        const float* __restrict__ bq, const float* __restrict__ bk,
        const float* __restrict__ bv,
        ushort* __restrict__ Qh, ushort* __restrict__ Kh, ushort* __restrict__ Vt) {
    __shared__ ushort As[128 * 64];   // 16KB
    __shared__ ushort Bs[128 * 64];   // 16KB
    const int tid = threadIdx.x;
    const int w = tid >> 6, lane = tid & 63;
    const int lr = lane & 15, lg = lane >> 4;
    int lid = (blockIdx.x & 7) * 96 + (blockIdx.x >> 3);
    const int tMg = (lid >> 3) << 7;
    const int tN  = (lid & 7) << 7;
    const int g   = tMg >> 12;                // 0=Q 1=K 2=V
    const ushort* W = Wall + (size_t)g * 1024 * 1024;
    const float* bias = (g == 0) ? bq : (g == 1 ? bk : bv);
    const int wr = (w >> 1) * 64, wc = (w & 1) * 64;

    f32x4 acc[4][4] = {};

    const ushort* gAsrc[4];
    const ushort* gBsrc[4];
#pragma unroll
    for (int i = 0; i < 4; i++) {
        int slot = (w * 4 + i) * 64 + lane;
        int row = slot >> 3, sr = slot & 7;
        int cd = sr ^ (row & 7);
        gAsrc[i] = A + (size_t)(tMg + row) * 1024 + cd * 8;
        gBsrc[i] = W + (size_t)(tN + row) * 1024 + cd * 8;
    }

    for (int k0 = 0; k0 < 1024; k0 += 64) {
#pragma unroll
        for (int i = 0; i < 4; i++)
            gld_lds16(gAsrc[i] + k0, As + (w * 4 + i) * 512);
#pragma unroll
        for (int i = 0; i < 4; i++)
            gld_lds16(gBsrc[i] + k0, Bs + (w * 4 + i) * 512);
        __syncthreads();

#pragma unroll
        for (int ks = 0; ks < 2; ks++) {
            bf16x8 af[4], bfr[4];
#pragma unroll
            for (int i = 0; i < 4; i++)
                af[i] = *(const bf16x8*)(As + (wr + i * 16 + lr) * 64 +
                                         (((ks * 4 + lg) ^ (lr & 7)) * 8));
#pragma unroll
            for (int i = 0; i < 4; i++)
                bfr[i] = *(const bf16x8*)(Bs + (wc + i * 16 + lr) * 64 +
                                          (((ks * 4 + lg) ^ (lr & 7)) * 8));
#pragma unroll
            for (int mi = 0; mi < 4; mi++)
#pragma unroll
                for (int ni = 0; ni < 4; ni++)
                    acc[mi][ni] = __builtin_amdgcn_mfma_f32_16x16x32_bf16(
                        af[mi], bfr[ni], acc[mi][ni], 0, 0, 0);
        }
        __syncthreads();
    }

#pragma unroll
    for (int mi = 0; mi < 4; mi++) {
        const int row0 = tMg + wr + mi * 16 + lg * 4;
#pragma unroll
        for (int ni = 0; ni < 4; ni++) {
            const int col = tN + wc + ni * 16 + lr;
            const int h = col >> 6, d = col & (DK - 1);
            const float bvv = bias[col];
            if (g == 2) {
                int mloc = row0 & 4095;
                int b = mloc >> 11, s0 = mloc & (SEQ - 1);
                ushort4 o4;
                o4.x = f2bf_u(acc[mi][ni][0] + bvv);
                o4.y = f2bf_u(acc[mi][ni][1] + bvv);
                o4.z = f2bf_u(acc[mi][ni][2] + bvv);
                o4.w = f2bf_u(acc[mi][ni][3] + bvv);
                *reinterpret_cast<ushort4*>(
                    &Vt[(((size_t)(b * NHEADS + h) * DK + d) * SEQ) + s0]) = o4;
            } else {
#pragma unroll
                for (int r = 0; r < 4; r++) {
                    float vv = acc[mi][ni][r] + bvv;
                    int mloc = (row0 + r) & 4095;
                    int b = mloc >> 11, s = mloc & (SEQ - 1);
                    if (g == 0)
                        Qh[(((size_t)(b * NHEADS + h) * SEQ + s) * DK) + d] = f2bf_u(vv);
                    else
                        Kh[(((size_t)(b * NHEADS + h) * SEQ + s) * DK) + d] = f2bf_u(vv);
                }
            }
        }
    }
}

// ---------------- output GEMM (64x128 tile, BK=64, XOR-swizzled LDS) ---------
__global__ __launch_bounds__(256) void gemm_out(
        const ushort* __restrict__ A,   // M x K bf16 row-major (ctx)
        const ushort* __restrict__ W,   // N x K bf16 row-major (Wo)
        const float* __restrict__ bias, // N
        float* __restrict__ out, int M, int N, int K) {
    __shared__ ushort As[64 * 64];     // 8KB
    __shared__ ushort Bs[128 * 64];    // 16KB
    const int tid = threadIdx.x;
    const int w = tid >> 6, lane = tid & 63;
    const int lr = lane & 15, lg = lane >> 4;
    const int nTiles = N >> 7;
    const int cpx = gridDim.x >> 3;
    int lid = (blockIdx.x & 7) * cpx + (blockIdx.x >> 3);
    const int tM = (lid / nTiles) << 6;
    const int tN = (lid % nTiles) << 7;
    const int wr = (w >> 1) * 32, wc = (w & 1) * 64;

    f32x4 acc[2][4] = {};

    const ushort* gAsrc[2];
    const ushort* gBsrc[4];
#pragma unroll
    for (int i = 0; i < 2; i++) {
        int slot = (w * 2 + i) * 64 + lane;
        int row = slot >> 3, sr = slot & 7;
        int cd = sr ^ (row & 7);
        gAsrc[i] = A + (size_t)(tM + row) * K + cd * 8;
    }
#pragma unroll
    for (int i = 0; i < 4; i++) {
        int slot = (w * 4 + i) * 64 + lane;
        int row = slot >> 3, sr = slot & 7;
        int cd = sr ^ (row & 7);
        gBsrc[i] = W + (size_t)(tN + row) * K + cd * 8;
    }

    for (int k0 = 0; k0 < K; k0 += 64) {
#pragma unroll
        for (int i = 0; i < 2; i++)
            gld_lds16(gAsrc[i] + k0, As + (w * 2 + i) * 512);
#pragma unroll
        for (int i = 0; i < 4; i++)
            gld_lds16(gBsrc[i] + k0, Bs + (w * 4 + i) * 512);
        __syncthreads();

#pragma unroll
        for (int ks = 0; ks < 2; ks++) {
            bf16x8 af[2], bfr[4];
#pragma unroll
            for (int i = 0; i < 2; i++)
                af[i] = *(const bf16x8*)(As + (wr + i * 16 + lr) * 64 +
                                         (((ks * 4 + lg) ^ (lr & 7)) * 8));
#pragma unroll
            for (int i = 0; i < 4; i++)
                bfr[i] = *(const bf16x8*)(Bs + (wc + i * 16 + lr) * 64 +
                                          (((ks * 4 + lg) ^ (lr & 7)) * 8));
#pragma unroll
            for (int mi = 0; mi < 2; mi++)
#pragma unroll
                for (int ni = 0; ni < 4; ni++)
                    acc[mi][ni] = __builtin_amdgcn_mfma_f32_16x16x32_bf16(
                        af[mi], bfr[ni], acc[mi][ni], 0, 0, 0);
        }
        __syncthreads();
    }

#pragma unroll
    for (int mi = 0; mi < 2; mi++) {
        const int row0 = tM + wr + mi * 16 + lg * 4;
#pragma unroll
        for (int ni = 0; ni < 4; ni++) {
            const int col = tN + wc + ni * 16 + lr;
            const float bv = bias[col];
#pragma unroll
            for (int r = 0; r < 4; r++)
                out[(size_t)(row0 + r) * N + col] = acc[mi][ni][r] + bv;
        }
    }
}

// ------- attention: KVBLK=64, no-max softmax, MFMA row-sum denominator -------
#define SCALE2 0.18033688011120542f   // 0.125 * log2(e)

__device__ __forceinline__ bf16x8 pack_pa(const float* p) {
    uint a, b, c, d;
    asm("v_cvt_pk_bf16_f32 %0, %1, %2" : "=v"(a) : "v"(p[0]), "v"(p[1]));
    asm("v_cvt_pk_bf16_f32 %0, %1, %2" : "=v"(b) : "v"(p[4]), "v"(p[5]));
    asm("v_cvt_pk_bf16_f32 %0, %1, %2" : "=v"(c) : "v"(p[2]), "v"(p[3]));
    asm("v_cvt_pk_bf16_f32 %0, %1, %2" : "=v"(d) : "v"(p[6]), "v"(p[7]));
    asm("v_permlane32_swap_b32 %0, %1" : "+v"(a), "+v"(b));
    asm("v_permlane32_swap_b32 %0, %1" : "+v"(c), "+v"(d));
    union { u32x4 u; bf16x8 h; } cv;
    cv.u = (u32x4){a, c, b, d};
    return cv.h;
}

__global__ __launch_bounds__(256) void attn_fwd32(
        const ushort* __restrict__ Qh, const ushort* __restrict__ Kh,
        const ushort* __restrict__ Vt, const float* __restrict__ mbias,
        ushort* __restrict__ ctx) {
    __shared__ ushort Ks[2][2][2048];
    __shared__ ushort Vs[2][2][2048];
    __shared__ float  Ml[SEQ];

    const int tid = threadIdx.x;
    const int w = tid >> 6;
    const int l = tid & 63;
    const int q32 = l & 31, hi = l >> 5;
    const int q7 = l & 7;

    int lid = (blockIdx.x & 7) * 64 + (blockIdx.x >> 3);
    const int qblk = lid & 15;
    const int bh = lid >> 4;
    const int b = bh >> 4;
    const int h = bh & 15;
    const int q0 = qblk * 128 + w * 32;

    const ushort* Qp = Qh + (size_t)bh * SEQ * DK + (size_t)(q0 + q32) * DK + hi * 8;
    const ushort* Kg = Kh + (size_t)bh * SEQ * DK;
    const ushort* Vg = Vt + (size_t)bh * DK * SEQ;

    const int srow = tid >> 3;
    const int scs  = (tid & 7) ^ (srow & 7);
    const ushort* Ksrc = Kg + (size_t)srow * DK + scs * 8;
    const ushort* Vsrc = Vg + (size_t)(srow + ((scs & 4) << 3)) * SEQ + (scs & 3) * 8;

    {
        const float* mg = mbias + (size_t)b * SEQ;
        gld_lds16(mg + tid * 4,        &Ml[w * 256]);
        gld_lds16(mg + 1024 + tid * 4, &Ml[1024 + w * 256]);
    }

    auto STAGE = [&](int buf, int t) {
        const int kv0 = t * 64;
        gld_lds16(Ksrc + (size_t)kv0 * DK,        &Ks[buf][0][w * 512]);
        gld_lds16(Ksrc + (size_t)(kv0 + 32) * DK, &Ks[buf][1][w * 512]);
        gld_lds16(Vsrc + kv0,                     &Vs[buf][0][w * 512]);
        gld_lds16(Vsrc + kv0 + 32,                &Vs[buf][1][w * 512]);
    };

    bf16x8 qf[4];
#pragma unroll
    for (int dc = 0; dc < 4; dc++)
        qf[dc] = *(const bf16x8*)(Qp + dc * 16);

    const short one_s = (short)0x3F80;
    const bf16x8 ones = {one_s, one_s, one_s, one_s, one_s, one_s, one_s, one_s};

    f32x16 c0 = {}, c1 = {};
    f32x16 lacc = {};

    STAGE(0, 0);
    __syncthreads();

    for (int t = 0; t < NT2; ++t) {
        const int buf = t & 1;
        if (t + 1 < NT2) STAGE(buf ^ 1, t + 1);

        const int kv0 = t * 64;

        bf16x8 kf0[4], kf1[4];
#pragma unroll
        for (int dc = 0; dc < 4; dc++)
            kf0[dc] = *(const bf16x8*)(&Ks[buf][0][q32 * 64 + (((dc * 2 + hi) ^ q7) * 8)]);
        f32x16 s0 = {}, s1 = {};
        __builtin_amdgcn_s_setprio(1);
#pragma unroll
        for (int dc = 0; dc < 4; dc++)
            s0 = __builtin_amdgcn_mfma_f32_32x32x16_bf16(kf0[dc], qf[dc], s0, 0, 0, 0);
        __builtin_amdgcn_s_setprio(0);
#pragma unroll
        for (int dc = 0; dc < 4; dc++)
            kf1[dc] = *(const bf16x8*)(&Ks[buf][1][q32 * 64 + (((dc * 2 + hi) ^ q7) * 8)]);
        __builtin_amdgcn_s_setprio(1);
#pragma unroll
        for (int dc = 0; dc < 4; dc++)
            s1 = __builtin_amdgcn_mfma_f32_32x32x16_bf16(kf1[dc], qf[dc], s1, 0, 0, 0);
        __builtin_amdgcn_s_setprio(0);

        float e0[16];
#pragma unroll
        for (int g = 0; g < 4; g++) {
            float4 mb0 = *reinterpret_cast<const float4*>(&Ml[kv0 + g * 8 + hi * 4]);
#pragma unroll
            for (int j = 0; j < 4; j++)
                e0[g * 4 + j] = __builtin_amdgcn_exp2f(
                    fmaf(s0[g * 4 + j], SCALE2, reinterpret_cast<const float*>(&mb0)[j]));
        }
        bf16x8 pa00 = pack_pa(e0);
        bf16x8 pa01 = pack_pa(e0 + 8);
        bf16x8 vc0[4];
#pragma unroll
        for (int dt = 0; dt < 2; dt++)
#pragma unroll
            for (int ks = 0; ks < 2; ks++)
                vc0[dt * 2 + ks] = *(const bf16x8*)(&Vs[buf][0][q32 * 64 + (((dt * 4 + ks * 2 + hi) ^ q7) * 8)]);
        __builtin_amdgcn_s_setprio(1);
        c0 = __builtin_amdgcn_mfma_f32_32x32x16_bf16(pa00, vc0[0], c0, 0, 0, 0);
        c1 = __builtin_amdgcn_mfma_f32_32x32x16_bf16(pa00, vc0[2], c1, 0, 0, 0);
        c0 = __builtin_amdgcn_mfma_f32_32x32x16_bf16(pa01, vc0[1], c0, 0, 0, 0);
        c1 = __builtin_amdgcn_mfma_f32_32x32x16_bf16(pa01, vc0[3], c1, 0, 0, 0);
        lacc = __builtin_amdgcn_mfma_f32_32x32x16_bf16(pa00, ones, lacc, 0, 0, 0);
        lacc = __builtin_amdgcn_mfma_f32_32x32x16_bf16(pa01, ones, lacc, 0, 0, 0);
        __builtin_amdgcn_s_setprio(0);

        float e1[16];
#pragma unroll
        for (int g = 0; g < 4; g++) {
            float4 mb1 = *reinterpret_cast<const float4*>(&Ml[kv0 + 32 + g * 8 + hi * 4]);
#pragma unroll
            for (int j = 0; j < 4; j++)
                e1[g * 4 + j] = __builtin_amdgcn_exp2f(
                    fmaf(s1[g * 4 + j], SCALE2, reinterpret_cast<const float*>(&mb1)[j]));
        }
        bf16x8 pa10 = pack_pa(e1);
        bf16x8 pa11 = pack_pa(e1 + 8);
        bf16x8 vc1[4];
#pragma unroll
        for (int dt = 0; dt < 2; dt++)
#pragma unroll
            for (int ks = 0; ks < 2; ks++)
                vc1[dt * 2 + ks] = *(const bf16x8*)(&Vs[buf][1][q32 * 64 + (((dt * 4 + ks * 2 + hi) ^ q7) * 8)]);
        __builtin_amdgcn_s_setprio(1);
        c0 = __builtin_amdgcn_mfma_f32_32x32x16_bf16(pa10, vc1[0], c0, 0, 0, 0);
        c1 = __builtin_amdgcn_mfma_f32_32x32x16_bf16(pa10, vc1[2], c1, 0, 0, 0);
        c0 = __builtin_amdgcn_mfma_f32_32x32x16_bf16(pa11, vc1[1], c0, 0, 0, 0);
        c1 = __builtin_amdgcn_mfma_f32_32x32x16_bf16(pa11, vc1[3], c1, 0, 0, 0);
        lacc = __builtin_amdgcn_mfma_f32_32x32x16_bf16(pa10, ones, lacc, 0, 0, 0);
        lacc = __builtin_amdgcn_mfma_f32_32x32x16_bf16(pa11, ones, lacc, 0, 0, 0);
        __builtin_amdgcn_s_setprio(0);

        __syncthreads();
    }

#pragma unroll
    for (int r = 0; r < 16; r++) {
        int crow = (r & 3) + 8 * (r >> 2) + 4 * hi;
        float rlT = __builtin_amdgcn_rcpf(lacc[r]);
        int qq = q0 + crow;
        size_t base = (size_t)(b * SEQ + qq) * DMODEL + h * DK;
        ctx[base + q32]      = f2bf_u(c0[r] * rlT);
        ctx[base + 32 + q32] = f2bf_u(c1[r] * rlT);
    }
}

extern "C" void kernel_launch(void* const* d_in, const int* in_sizes, int n_in,
                              void* d_out, int out_size, void* d_ws, size_t ws_size,
                              hipStream_t stream) {
    const float* q    = (const float*)d_in[0];
    const float* k    = (const float*)d_in[1];
    const float* v    = (const float*)d_in[2];
    const int*   mask = (const int*)d_in[3];
    const float* Wq   = (const float*)d_in[4];
    const float* bq   = (const float*)d_in[5];
    const float* Wk   = (const float*)d_in[6];
    const float* bk   = (const float*)d_in[7];
    const float* Wv   = (const float*)d_in[8];
    const float* bv   = (const float*)d_in[9];
    const float* Wo   = (const float*)d_in[10];
    const float* bo   = (const float*)d_in[11];

    char* ws = (char*)d_ws;
    ushort* qb   = (ushort*)(ws + (size_t)0);          // [qb|kb|vb] = 12288x1024
    ushort* kb   = (ushort*)(ws + ((size_t)8  << 20));
    ushort* vb   = (ushort*)(ws + ((size_t)16 << 20));
    ushort* Wqb  = (ushort*)(ws + ((size_t)24 << 20)); // [Wqb|Wkb|Wvb]
    ushort* Wkb  = (ushort*)(ws + ((size_t)26 << 20));
    ushort* Wvb  = (ushort*)(ws + ((size_t)28 << 20));
    ushort* Wob  = (ushort*)(ws + ((size_t)30 << 20));
    ushort* Qh   = (ushort*)(ws + ((size_t)32 << 20));
    ushort* Kh   = (ushort*)(ws + ((size_t)40 << 20));
    ushort* Vt   = (ushort*)(ws + ((size_t)48 << 20));
    ushort* ctxb = (ushort*)(ws + ((size_t)56 << 20));
    float*  mbias = (float*)d_out;   // written by cast_all, read by attn,
                                     // then d_out fully overwritten by gemm_out

    cast_all<<<16388, 256, 0, stream>>>(q, k, v, Wq, Wk, Wv, Wo, mask,
                                        qb, kb, vb, Wqb, Wkb, Wvb, Wob, mbias);

    gemm_qkv<<<768, 256, 0, stream>>>(qb, Wqb, bq, bk, bv, Qh, Kh, Vt);

    attn_fwd32<<<BATCH * NHEADS * (SEQ / 128), 256, 0, stream>>>(Qh, Kh, Vt, mbias, ctxb);

    const int M = BATCH * SEQ;
    gemm_out<<<(M / 64) * (DMODEL / 128), 256, 0, stream>>>(
        ctxb, Wob, bo, (float*)d_out, M, DMODEL, DMODEL);
}